// Round 6
// baseline (118.992 us; speedup 1.0000x reference)
//
#include <hip/hip_runtime.h>
#include <math.h>

// Problem constants (fixed by setup_inputs)
#define BSZ    2
#define LFULL  4096
#define MLEN   2048      // M = hidden_states.shape[1]
#define DMODEL 2048
#define CLIP_EPS 1e-4f
#define CCH    256       // number of chunks
#define TCH    8         // chunk length; CCH*TCH == MLEN

typedef float f4 __attribute__((ext_vector_type(4)));

// ---------------------------------------------------------------------------
// MEGA: the entire layer in ONE dispatch, zero cross-block communication.
//
// block = (16-float column strip bx, batch b); 1024 threads = 256 chunks (c)
// x 4 f4-lanes (j). Every block REDUNDANTLY computes the (tiny) prep for its
// batch from bmask/bprob (L2-resident after first touch), so no producer
// kernel, no launch gap, no global prep arrays:
//   - stable partition sel[] via block-local prefix scan (256-thr sections,
//     all-thread barriers)
//   - per-thread own-chunk params: w=p/dt, e=1-p, cde (running product),
//     scatter ranges [ls,le) -- all from sel + bprob, registers only
//   - chunk product Pc[c] == own cde[7] -> feeds the scan's sP directly
// Then: local chunk scan in registers (xr), block-local Hillis-Steele over
// all 256 chunks (LDS), epilogue y = xr + cde*H, NT scatter to out.
// All arithmetic bit-identical to the verified R5 pipeline.
//
// grid: (DMODEL/16, BSZ) = (128, 2) = 256 blocks x 1024 threads.
// LDS: union(prep 9.2 KB, scan 17 KB) = 17 KB. LB(1024,2) -> <=256 VGPR,
// so the 8xf4 xr loads issue before the prep phase (no R3-style sinking).
// ---------------------------------------------------------------------------
__global__ __launch_bounds__(1024, 2) void mega(
    const float* __restrict__ hid, const int* __restrict__ bmask_raw,
    const float* __restrict__ bprob, float* __restrict__ out)
{
  const int tid = threadIdx.x;
  const int j   = tid & 3;          // f4 lane within the 16-float strip
  const int c   = tid >> 2;         // chunk [0, 256)
  const int bx  = blockIdx.x;       // strip [0, 128)
  const int b   = blockIdx.y;       // batch

  __shared__ union {
    struct { int cnt[257]; int mode; int ntrue; int sel[MLEN]; } k1;  // 9.2 KB
    struct { float P[CCH]; f4 S[CCH][4]; } scan;                      // 17 KB
  } sm;

  // ---- phase A: issue this block's hid loads (33.5 MB grid-wide in
  //      flight; the redundant prep below runs under this latency) ----
  const int d4 = bx * 4 + j;        // f4 column index [0, 512)
  const int o  = b * MLEN + c * TCH;
  const f4* xp = (const f4*)hid + ((size_t)o * DMODEL >> 2) + d4;
  f4 xr[TCH];
  #pragma unroll
  for (int t = 0; t < TCH; ++t) xr[t] = xp[(size_t)t * (DMODEL / 4)];

  // ---- phase B: redundant prep (per batch), 256-thr work sections ----
  if (tid == 0) {
    unsigned w0 = ((const unsigned*)bmask_raw)[0];
    sm.k1.mode = (w0 <= 1u) ? 1 : 0;  // 1: int32 per element, 0: uint8
  }
  __syncthreads();
  const int mode = sm.k1.mode;
  const unsigned char* bmask_u8 = (const unsigned char*)bmask_raw;

  const int PER = LFULL / 256;      // 16 positions per (low) thread
  if (tid < 256) {
    const int base = tid * PER;
    int cnt = 0;
    for (int i = 0; i < PER; ++i) {
      const int L = base + i;
      const int v = mode ? (bmask_raw[b * LFULL + L] != 0)
                         : (bmask_u8[b * LFULL + L] != 0);
      cnt += v;
    }
    sm.k1.cnt[tid] = cnt;
  }
  __syncthreads();

  // Exclusive prefix over 256 counts: wave 0, lane i owns entries 4i..4i+3.
  if (tid < 64) {
    const int q = tid * 4;
    const int c0 = sm.k1.cnt[q], c1 = sm.k1.cnt[q + 1];
    const int c2 = sm.k1.cnt[q + 2], c3 = sm.k1.cnt[q + 3];
    const int mysum = c0 + c1 + c2 + c3;
    int incl = mysum;
    #pragma unroll
    for (int off = 1; off < 64; off <<= 1) {
      const int v = __shfl_up(incl, off, 64);
      if (tid >= off) incl += v;
    }
    const int excl = incl - mysum;
    sm.k1.cnt[q]     = excl;
    sm.k1.cnt[q + 1] = excl + c0;
    sm.k1.cnt[q + 2] = excl + c0 + c1;
    sm.k1.cnt[q + 3] = excl + c0 + c1 + c2;
    if (tid == 63) { sm.k1.cnt[256] = incl; sm.k1.ntrue = incl; }
  }
  __syncthreads();
  const int ntrue = sm.k1.ntrue;

  // Fill sel: boundary positions (rank) then non-boundary (ntrue + false-rank)
  if (tid < 256) {
    const int base = tid * PER;
    int trun = sm.k1.cnt[tid];
    for (int i = 0; i < PER; ++i) {
      const int L = base + i;
      const int v = mode ? (bmask_raw[b * LFULL + L] != 0)
                         : (bmask_u8[b * LFULL + L] != 0);
      if (v) {
        if (trun < MLEN) sm.k1.sel[trun] = L;
        ++trun;
      } else {
        const int f = L - trun;         // falses strictly before L
        const int slot = ntrue + f;
        if (slot < MLEN) sm.k1.sel[slot] = L;
      }
    }
  }
  __syncthreads();

  // Own-chunk params straight to registers (4 j-lanes compute redundantly).
  // Bit-identical formulas: w = p/dt, e = 1-p, cde = running product.
  const int nb = (ntrue < MLEN) ? ntrue : MLEN;
  float w[TCH], e[TCH], cd[TCH];
  int   ls[TCH], le[TCH];
  {
    float run = 1.0f;
    #pragma unroll
    for (int t = 0; t < TCH; ++t) {
      const int g = c * TCH + t;        // global selected index [0, MLEN)
      const int L = sm.k1.sel[g];
      float p = bprob[((size_t)b * LFULL + L) * 2 + 1];
      p = fminf(fmaxf(p, CLIP_EPS), 1.0f - CLIP_EPS);
      const float dt = -log1pf(-p);     // log(1/(1-p))
      w[t] = p / dt;
      e[t] = 1.0f - p;                  // exp(-dt) exactly
      run *= e[t];
      cd[t] = run;
      // scatter range for g (same logic as verified k1)
      if (nb == 0) {
        ls[t] = (g == 0) ? 0 : LFULL;
        le[t] = (g == 0) ? LFULL : LFULL;
      } else if (g < nb) {
        ls[t] = (g == 0) ? 0 : sm.k1.sel[g];
        le[t] = (g == nb - 1) ? LFULL : sm.k1.sel[g + 1];
      } else {
        ls[t] = LFULL; le[t] = LFULL;   // empty
      }
    }
  }
  __syncthreads();                      // done with k1 LDS; repurpose union

  // ---- phase C: local chunk scan in registers; publish S, P to LDS ----
  f4 st = {0.f, 0.f, 0.f, 0.f};
  #pragma unroll
  for (int t = 0; t < TCH; ++t) {
    const f4 x = xr[t];
    st.x = fmaf(e[t], st.x, w[t] * x.x);
    st.y = fmaf(e[t], st.y, w[t] * x.y);
    st.z = fmaf(e[t], st.z, w[t] * x.z);
    st.w = fmaf(e[t], st.w, w[t] * x.w);
    xr[t] = st;                         // running local state at position t
  }
  sm.scan.S[c][j] = st;
  if (j == 0) sm.scan.P[c] = cd[TCH - 1];   // Pc[c] == own chunk product
  __syncthreads();

  // ---- phase D: Hillis-Steele over 256 chunks (identical to k25 math) ----
  for (int dstep = 1; dstep < CCH; dstep <<= 1) {
    const float pc = sm.scan.P[c];
    float pd = 1.0f;
    f4 sd = {0.f, 0.f, 0.f, 0.f};
    if (c >= dstep) { pd = sm.scan.P[c - dstep]; sd = sm.scan.S[c - dstep][j]; }
    __syncthreads();
    if (c >= dstep) {
      f4 cur = sm.scan.S[c][j];
      cur.x = fmaf(pc, sd.x, cur.x);
      cur.y = fmaf(pc, sd.y, cur.y);
      cur.z = fmaf(pc, sd.z, cur.z);
      cur.w = fmaf(pc, sd.w, cur.w);
      sm.scan.S[c][j] = cur;
      if (j == 0) sm.scan.P[c] = pc * pd;
    }
    __syncthreads();
  }

  // exclusive shift: carry-in for chunk c is inclusive scan at c-1
  f4 H = {0.f, 0.f, 0.f, 0.f};
  if (c > 0) H = sm.scan.S[c - 1][j];

  // ---- phase E: y = xr + cde*H, NT scatter to out rows [ls, le) ----
  f4* op = (f4*)out + ((size_t)b * LFULL * DMODEL >> 2) + d4;
  #pragma unroll
  for (int t = 0; t < TCH; ++t) {
    f4 y;
    y.x = fmaf(cd[t], H.x, xr[t].x);
    y.y = fmaf(cd[t], H.y, xr[t].y);
    y.z = fmaf(cd[t], H.z, xr[t].z);
    y.w = fmaf(cd[t], H.w, xr[t].w);
    for (int L = ls[t]; L < le[t]; ++L) {
      __builtin_nontemporal_store(y, op + (size_t)L * (DMODEL / 4));
    }
  }
}

// ---------------------------------------------------------------------------
extern "C" void kernel_launch(void* const* d_in, const int* in_sizes, int n_in,
                              void* d_out, int out_size, void* d_ws, size_t ws_size,
                              hipStream_t stream) {
  const float* hid   = (const float*)d_in[0];   // (2, 2048, 2048) fp32
  const int*   bmask = (const int*)d_in[1];     // (2, 4096) bool (layout sniffed)
  const float* bprob = (const float*)d_in[2];   // (2, 4096, 2) fp32
  float*       out   = (float*)d_out;           // (2, 4096, 2048) fp32
  (void)d_ws; (void)ws_size;

  mega<<<dim3(DMODEL / 16, BSZ), dim3(1024), 0, stream>>>(hid, bmask, bprob, out);
}

// Round 7
// 116.608 us; speedup vs baseline: 1.0204x; 1.0204x over previous
//
#include <hip/hip_runtime.h>
#include <math.h>

// Problem constants (fixed by setup_inputs)
#define BSZ    2
#define LFULL  4096
#define MLEN   2048      // M = hidden_states.shape[1]
#define DMODEL 2048
#define CLIP_EPS 1e-4f
#define CCH    256       // number of chunks
#define TCH    8         // chunk length; CCH*TCH == MLEN

typedef float f4 __attribute__((ext_vector_type(4)));

// ---------------------------------------------------------------------------
// MEGA v2: entire layer in ONE dispatch, zero cross-block communication.
//
// block = (16-float column strip bx, batch b); 1024 threads = 256 chunks (c)
// x 4 f4-lanes (j). Every block redundantly computes the prep for its batch.
//
// v2 fixes (from R6 counters: VGPR=52 -> loads sunk; 2.3 TB/s effective):
//  - xr loads kept alive via empty asm BEFORE prep -> hid stream overlaps
//    the prep latency instead of serializing after it.
//  - sel[] stays resident in LDS (no union with scan) so ls/le are
//    recomputed at store time: 16 fewer live VGPRs, no spills.
//  - prep count/fill passes use all 1024 threads (4 positions each) with a
//    two-level (shfl + wave-offset) prefix scan.
// All arithmetic bit-identical to the verified pipeline.
//
// grid: (DMODEL/16, BSZ) = (128, 2) = 256 blocks x 1024 threads.
// LDS: sel 8KB + S 16KB + P 1KB + misc ~= 25.3 KB (1 block/CU by threads).
// ---------------------------------------------------------------------------
__global__ __launch_bounds__(1024, 2) void mega(
    const float* __restrict__ hid, const int* __restrict__ bmask_raw,
    const float* __restrict__ bprob, float* __restrict__ out)
{
  const int tid = threadIdx.x;
  const int j   = tid & 3;          // f4 lane within the 16-float strip
  const int c   = tid >> 2;         // chunk [0, 256)
  const int bx  = blockIdx.x;       // strip [0, 128)
  const int b   = blockIdx.y;       // batch

  __shared__ int   s_sel[MLEN];     // 8 KB, alive through the epilogue
  __shared__ float s_P[CCH];        // 1 KB
  __shared__ f4    s_S[CCH][4];     // 16 KB
  __shared__ int   s_wtot[16];      // per-wave counts -> exclusive offsets
  __shared__ int   s_mode, s_ntrue;

  // ---- phase A: issue this block's hid loads; keep-alive pins them ----
  const int d4 = bx * 4 + j;        // f4 column index [0, 512)
  const int o  = b * MLEN + c * TCH;
  const f4* xp = (const f4*)hid + ((size_t)o * DMODEL >> 2) + d4;
  f4 xr[TCH];
  #pragma unroll
  for (int t = 0; t < TCH; ++t) xr[t] = xp[(size_t)t * (DMODEL / 4)];
  #pragma unroll
  for (int t = 0; t < TCH; ++t) asm volatile("" : "+v"(xr[t]));

  // ---- phase B: redundant prep, all 1024 threads (4 positions each) ----
  if (tid == 0) {
    unsigned w0 = ((const unsigned*)bmask_raw)[0];
    s_mode = (w0 <= 1u) ? 1 : 0;    // 1: int32 per element, 0: uint8
  }
  __syncthreads();
  const int mode = s_mode;
  const unsigned char* bmask_u8 = (const unsigned char*)bmask_raw;

  const int PER  = LFULL / 1024;    // 4 positions per thread
  const int base = tid * PER;

  int cnt = 0;
  {
    #pragma unroll
    for (int i = 0; i < PER; ++i) {
      const int L = base + i;
      const int v = mode ? (bmask_raw[b * LFULL + L] != 0)
                         : (bmask_u8[b * LFULL + L] != 0);
      cnt += v;
    }
  }

  // two-level exclusive prefix over 1024 per-thread counts
  const int lane = tid & 63, wv = tid >> 6;
  int incl = cnt;
  #pragma unroll
  for (int off = 1; off < 64; off <<= 1) {
    const int v = __shfl_up(incl, off, 64);
    if (lane >= off) incl += v;
  }
  if (lane == 63) s_wtot[wv] = incl;     // wave totals
  __syncthreads();
  if (tid == 0) {
    int run = 0;
    #pragma unroll
    for (int w = 0; w < 16; ++w) { const int t = s_wtot[w]; s_wtot[w] = run; run += t; }
    s_ntrue = run;
  }
  __syncthreads();
  const int excl  = (incl - cnt) + s_wtot[wv];
  const int ntrue = s_ntrue;

  // fill sel: boundary positions (rank) then non-boundary (ntrue + false-rank)
  {
    int trun = excl;
    #pragma unroll
    for (int i = 0; i < PER; ++i) {
      const int L = base + i;
      const int v = mode ? (bmask_raw[b * LFULL + L] != 0)
                         : (bmask_u8[b * LFULL + L] != 0);
      if (v) {
        if (trun < MLEN) s_sel[trun] = L;
        ++trun;
      } else {
        const int f = L - trun;          // falses strictly before L
        const int slot = ntrue + f;
        if (slot < MLEN) s_sel[slot] = L;
      }
    }
  }
  __syncthreads();

  // own-chunk params to registers (4 j-lanes compute redundantly);
  // bit-identical formulas: w = p/dt, e = 1-p, cde = running product.
  float w[TCH], e[TCH], cd[TCH];
  {
    float run = 1.0f;
    #pragma unroll
    for (int t = 0; t < TCH; ++t) {
      const int L = s_sel[c * TCH + t];
      float p = bprob[((size_t)b * LFULL + L) * 2 + 1];
      p = fminf(fmaxf(p, CLIP_EPS), 1.0f - CLIP_EPS);
      const float dt = -log1pf(-p);      // log(1/(1-p))
      w[t] = p / dt;
      e[t] = 1.0f - p;                   // exp(-dt) exactly
      run *= e[t];
      cd[t] = run;
    }
  }

  // ---- phase C: local chunk scan in registers; publish S, P ----
  f4 st = {0.f, 0.f, 0.f, 0.f};
  #pragma unroll
  for (int t = 0; t < TCH; ++t) {
    const f4 x = xr[t];
    st.x = fmaf(e[t], st.x, w[t] * x.x);
    st.y = fmaf(e[t], st.y, w[t] * x.y);
    st.z = fmaf(e[t], st.z, w[t] * x.z);
    st.w = fmaf(e[t], st.w, w[t] * x.w);
    xr[t] = st;                          // running local state at position t
  }
  s_S[c][j] = st;
  if (j == 0) s_P[c] = cd[TCH - 1];      // chunk product
  __syncthreads();

  // ---- phase D: Hillis-Steele over 256 chunks (identical to k25 math) ----
  for (int dstep = 1; dstep < CCH; dstep <<= 1) {
    const float pc = s_P[c];
    float pd = 1.0f;
    f4 sd = {0.f, 0.f, 0.f, 0.f};
    if (c >= dstep) { pd = s_P[c - dstep]; sd = s_S[c - dstep][j]; }
    __syncthreads();
    if (c >= dstep) {
      f4 cur = s_S[c][j];
      cur.x = fmaf(pc, sd.x, cur.x);
      cur.y = fmaf(pc, sd.y, cur.y);
      cur.z = fmaf(pc, sd.z, cur.z);
      cur.w = fmaf(pc, sd.w, cur.w);
      s_S[c][j] = cur;
      if (j == 0) s_P[c] = pc * pd;
    }
    __syncthreads();
  }

  // exclusive shift: carry-in for chunk c is inclusive scan at c-1
  f4 H = {0.f, 0.f, 0.f, 0.f};
  if (c > 0) H = s_S[c - 1][j];

  // ---- phase E: y = xr + cde*H, NT scatter to rows [ls, le) from s_sel ----
  const int nb = (ntrue < MLEN) ? ntrue : MLEN;
  f4* op = (f4*)out + ((size_t)b * LFULL * DMODEL >> 2) + d4;
  #pragma unroll
  for (int t = 0; t < TCH; ++t) {
    const int g = c * TCH + t;           // global selected index [0, MLEN)
    int ls, le;
    if (nb == 0) {
      ls = (g == 0) ? 0 : LFULL;
      le = (g == 0) ? LFULL : LFULL;
    } else if (g < nb) {
      ls = (g == 0) ? 0 : s_sel[g];
      le = (g == nb - 1) ? LFULL : s_sel[g + 1];
    } else {
      ls = LFULL; le = LFULL;            // empty
    }
    f4 y;
    y.x = fmaf(cd[t], H.x, xr[t].x);
    y.y = fmaf(cd[t], H.y, xr[t].y);
    y.z = fmaf(cd[t], H.z, xr[t].z);
    y.w = fmaf(cd[t], H.w, xr[t].w);
    for (int L = ls; L < le; ++L) {
      __builtin_nontemporal_store(y, op + (size_t)L * (DMODEL / 4));
    }
  }
}

// ---------------------------------------------------------------------------
extern "C" void kernel_launch(void* const* d_in, const int* in_sizes, int n_in,
                              void* d_out, int out_size, void* d_ws, size_t ws_size,
                              hipStream_t stream) {
  const float* hid   = (const float*)d_in[0];   // (2, 2048, 2048) fp32
  const int*   bmask = (const int*)d_in[1];     // (2, 4096) bool (layout sniffed)
  const float* bprob = (const float*)d_in[2];   // (2, 4096, 2) fp32
  float*       out   = (float*)d_out;           // (2, 4096, 2048) fp32
  (void)d_ws; (void)ws_size;

  mega<<<dim3(DMODEL / 16, BSZ), dim3(1024), 0, stream>>>(hid, bmask, bprob, out);
}